// Round 1
// baseline (391.907 us; speedup 1.0000x reference)
//
#include <hip/hip_runtime.h>

typedef unsigned short u16;
typedef unsigned int u32;

#define DM 1024
#define NH 16
#define DH 64
#define BB 2
#define TT 2048

using frag8  = __attribute__((ext_vector_type(8))) short;
using bf16x8 = __attribute__((ext_vector_type(8))) __bf16;
using f32x4  = __attribute__((ext_vector_type(4))) float;

__device__ inline u16 f2bf(float f) {
  union { float f; u32 u; } v; v.f = f;
  u32 r = v.u + 0x7fffu + ((v.u >> 16) & 1u);
  return (u16)(r >> 16);
}

__device__ inline f32x4 mfma_bf16(frag8 a, frag8 b, f32x4 c) {
  return __builtin_amdgcn_mfma_f32_16x16x32_bf16(
      __builtin_bit_cast(bf16x8, a), __builtin_bit_cast(bf16x8, b), c, 0, 0, 0);
}

// ---------- x -> bf16 ----------
__global__ __launch_bounds__(256) void cvt_x_kernel(const float* __restrict__ X,
                                                    u16* __restrict__ Y) {
  int i = blockIdx.x * 256 + threadIdx.x;  // over float4 groups
  float4 v = ((const float4*)X)[i];
  ushort4 o;
  o.x = f2bf(v.x); o.y = f2bf(v.y); o.z = f2bf(v.z); o.w = f2bf(v.w);
  ((ushort4*)Y)[i] = o;
}

// ---------- W (K,N) fp32 -> Wt (N,K) bf16, tiled ----------
__global__ __launch_bounds__(256) void transpose_w_kernel(
    const float* __restrict__ W0, const float* __restrict__ W1,
    const float* __restrict__ W2, const float* __restrict__ W3,
    u16* __restrict__ O0, u16* __restrict__ O1,
    u16* __restrict__ O2, u16* __restrict__ O3) {
  const float* W; u16* Ot;
  switch (blockIdx.z) {
    case 0: W = W0; Ot = O0; break;
    case 1: W = W1; Ot = O1; break;
    case 2: W = W2; Ot = O2; break;
    default: W = W3; Ot = O3; break;
  }
  __shared__ u16 Ls[64][72];
  int tid = threadIdx.x;
  int n0 = blockIdx.x * 64;
  int k0 = blockIdx.y * 64;
#pragma unroll
  for (int p = 0; p < 4; ++p) {
    int id = tid + p * 256;
    int row = id >> 4;           // k local
    int c4 = (id & 15) * 4;      // n local
    float4 v = *(const float4*)&W[(size_t)(k0 + row) * DM + n0 + c4];
    ushort4 o; o.x = f2bf(v.x); o.y = f2bf(v.y); o.z = f2bf(v.z); o.w = f2bf(v.w);
    *(ushort4*)&Ls[row][c4] = o;
  }
  __syncthreads();
#pragma unroll
  for (int p = 0; p < 4; ++p) {
    int id = tid + p * 256;
    int row = id >> 4;           // n local (output row)
    int c4 = (id & 15) * 4;      // k local
    ushort4 o;
    o.x = Ls[c4 + 0][row]; o.y = Ls[c4 + 1][row];
    o.z = Ls[c4 + 2][row]; o.w = Ls[c4 + 3][row];
    *(ushort4*)&Ot[(size_t)(n0 + row) * DM + k0 + c4] = o;
  }
}

// ---------- C = A @ Bt^T + bias  (A: M x K bf16, Bt: N x K bf16) ----------
// M=4096, N=K=1024. 128x128 tile, BK=32, 256 threads, 4 waves, 4x4 MFMA tiles/wave.
template <bool F32OUT>
__global__ __launch_bounds__(256) void gemm_bt_kernel(
    const u16* __restrict__ A, const u16* __restrict__ Bt,
    const float* __restrict__ bias, void* __restrict__ Cout) {
  constexpr int K = DM, N = DM;
  __shared__ u16 As[128][40];
  __shared__ u16 Bs[128][40];
  int tid = threadIdx.x;
  int lane = tid & 63, wave = tid >> 6;
  int qd = lane >> 4, ln = lane & 15;
  int wm = (wave & 1) * 64, wn = (wave >> 1) * 64;
  int m0 = blockIdx.y * 128, n0 = blockIdx.x * 128;
  f32x4 z = {0.f, 0.f, 0.f, 0.f};
  f32x4 acc[4][4];
#pragma unroll
  for (int mi = 0; mi < 4; ++mi)
#pragma unroll
    for (int ni = 0; ni < 4; ++ni) acc[mi][ni] = z;

  for (int k0 = 0; k0 < K; k0 += 32) {
#pragma unroll
    for (int p = 0; p < 2; ++p) {
      int id = tid + p * 256;
      int row = id >> 2, seg = id & 3;
      *(uint4*)&As[row][seg * 8] =
          *(const uint4*)&A[(size_t)(m0 + row) * K + k0 + seg * 8];
      *(uint4*)&Bs[row][seg * 8] =
          *(const uint4*)&Bt[(size_t)(n0 + row) * K + k0 + seg * 8];
    }
    __syncthreads();
    frag8 a[4], b[4];
#pragma unroll
    for (int mi = 0; mi < 4; ++mi)
      a[mi] = *(const frag8*)&As[wm + mi * 16 + ln][qd * 8];
#pragma unroll
    for (int ni = 0; ni < 4; ++ni)
      b[ni] = *(const frag8*)&Bs[wn + ni * 16 + ln][qd * 8];
#pragma unroll
    for (int mi = 0; mi < 4; ++mi)
#pragma unroll
      for (int ni = 0; ni < 4; ++ni)
        acc[mi][ni] = mfma_bf16(a[mi], b[ni], acc[mi][ni]);
    __syncthreads();
  }

#pragma unroll
  for (int mi = 0; mi < 4; ++mi)
#pragma unroll
    for (int ni = 0; ni < 4; ++ni)
#pragma unroll
      for (int r = 0; r < 4; ++r) {
        int row = m0 + wm + mi * 16 + qd * 4 + r;
        int col = n0 + wn + ni * 16 + ln;
        float v = acc[mi][ni][r] + bias[col];
        if constexpr (F32OUT)
          ((float*)Cout)[(size_t)row * N + col] = v;
        else
          ((u16*)Cout)[(size_t)row * N + col] = f2bf(v);
      }
}

// ---------- V (B,T,D) bf16 -> Vt (B,H,DH,T) bf16, tiled ----------
__global__ __launch_bounds__(256) void transpose_v_kernel(const u16* __restrict__ V,
                                                          u16* __restrict__ Vt) {
  int bh = blockIdx.y;
  int b = bh >> 4, h = bh & 15;
  int t0 = blockIdx.x * 64;
  __shared__ u16 Ls[64][72];
  int tid = threadIdx.x;
#pragma unroll
  for (int p = 0; p < 2; ++p) {
    int id = tid + p * 256;
    int row = id >> 3, seg = id & 7;  // row = t local, seg*8 = d chunk
    *(uint4*)&Ls[row][seg * 8] =
        *(const uint4*)&V[(size_t)(b * TT + t0 + row) * DM + h * DH + seg * 8];
  }
  __syncthreads();
#pragma unroll
  for (int p = 0; p < 2; ++p) {
    int id = tid + p * 256;
    int d = id >> 3, seg = id & 7;  // output row = d, seg*8 = t chunk
    union { u16 s[8]; uint4 v; } tmp;
#pragma unroll
    for (int j = 0; j < 8; ++j) tmp.s[j] = Ls[seg * 8 + j][d];
    *(uint4*)&Vt[(size_t)(bh * DH + d) * TT + t0 + seg * 8] = tmp.v;
  }
}

// ---------- flash attention: per (b,h), 64-row Q tile, causal ----------
__global__ __launch_bounds__(256) void flash_kernel(const u16* __restrict__ Q,
                                                    const u16* __restrict__ K,
                                                    const u16* __restrict__ Vt,
                                                    u16* __restrict__ O) {
  int qt = blockIdx.x, bh = blockIdx.y;
  int b = bh >> 4, h = bh & 15;
  int q0 = qt * 64;
  __shared__ u16 Qs[64][72];
  __shared__ u16 Ks[64][72];
  __shared__ u16 Vs[64][72];
  __shared__ u16 Ps[64][72];
  int tid = threadIdx.x;
  int lane = tid & 63, wave = tid >> 6;
  int qd = lane >> 4, ln = lane & 15;

#pragma unroll
  for (int p = 0; p < 2; ++p) {
    int id = tid + p * 256;
    int row = id >> 3, seg = id & 7;
    *(uint4*)&Qs[row][seg * 8] =
        *(const uint4*)&Q[(size_t)(b * TT + q0 + row) * DM + h * DH + seg * 8];
  }

  float m_st[4] = {-INFINITY, -INFINITY, -INFINITY, -INFINITY};
  float l_st[4] = {0.f, 0.f, 0.f, 0.f};
  f32x4 z = {0.f, 0.f, 0.f, 0.f};
  f32x4 o_acc[4] = {z, z, z, z};

  for (int kt = 0; kt <= qt; ++kt) {
    __syncthreads();  // protect prior iteration's Ks/Vs reads
#pragma unroll
    for (int p = 0; p < 2; ++p) {
      int id = tid + p * 256;
      int row = id >> 3, seg = id & 7;
      *(uint4*)&Ks[row][seg * 8] =
          *(const uint4*)&K[(size_t)(b * TT + kt * 64 + row) * DM + h * DH + seg * 8];
      *(uint4*)&Vs[row][seg * 8] =
          *(const uint4*)&Vt[(size_t)(bh * DH + row) * TT + kt * 64 + seg * 8];
    }
    __syncthreads();

    // S = Q K^T  (wave handles rows wave*16..wave*16+15, all 64 cols)
    f32x4 s[4] = {z, z, z, z};
#pragma unroll
    for (int kk = 0; kk < 2; ++kk) {
      frag8 aq = *(const frag8*)&Qs[wave * 16 + ln][kk * 32 + qd * 8];
#pragma unroll
      for (int ni = 0; ni < 4; ++ni) {
        frag8 bk = *(const frag8*)&Ks[ni * 16 + ln][kk * 32 + qd * 8];
        s[ni] = mfma_bf16(aq, bk, s[ni]);
      }
    }

    float sv[4][4];
    bool diag = (kt == qt);
#pragma unroll
    for (int ni = 0; ni < 4; ++ni)
#pragma unroll
      for (int r = 0; r < 4; ++r) {
        float v = s[ni][r] * 0.125f;  // 1/sqrt(64)
        if (diag) {
          int qrow = q0 + wave * 16 + qd * 4 + r;
          int kcol = kt * 64 + ni * 16 + ln;
          if (kcol > qrow) v = -INFINITY;
        }
        sv[ni][r] = v;
      }

#pragma unroll
    for (int r = 0; r < 4; ++r) {
      float m = fmaxf(fmaxf(sv[0][r], sv[1][r]), fmaxf(sv[2][r], sv[3][r]));
#pragma unroll
      for (int off = 1; off < 16; off <<= 1) m = fmaxf(m, __shfl_xor(m, off));
      float mnew = fmaxf(m_st[r], m);
      float alpha = __expf(m_st[r] - mnew);  // exp(-inf)=0 first iter
      m_st[r] = mnew;
      l_st[r] *= alpha;
#pragma unroll
      for (int ni = 0; ni < 4; ++ni) o_acc[ni][r] *= alpha;
      float ps = 0.f;
#pragma unroll
      for (int ni = 0; ni < 4; ++ni) {
        float p = __expf(sv[ni][r] - mnew);
        sv[ni][r] = p;
        ps += p;
      }
#pragma unroll
      for (int off = 1; off < 16; off <<= 1) ps += __shfl_xor(ps, off);
      l_st[r] += ps;
    }

    // P: C-layout -> LDS -> A-layout (wave-private rows, no cross-wave use)
#pragma unroll
    for (int ni = 0; ni < 4; ++ni)
#pragma unroll
      for (int r = 0; r < 4; ++r)
        Ps[wave * 16 + qd * 4 + r][ni * 16 + ln] = f2bf(sv[ni][r]);
    __syncthreads();

    // O += P @ V   (B operand = Vt tile, (n=d, k=t) layout)
#pragma unroll
    for (int kk = 0; kk < 2; ++kk) {
      frag8 ap = *(const frag8*)&Ps[wave * 16 + ln][kk * 32 + qd * 8];
#pragma unroll
      for (int ni = 0; ni < 4; ++ni) {
        frag8 bv = *(const frag8*)&Vs[ni * 16 + ln][kk * 32 + qd * 8];
        o_acc[ni] = mfma_bf16(ap, bv, o_acc[ni]);
      }
    }
  }

#pragma unroll
  for (int ni = 0; ni < 4; ++ni)
#pragma unroll
    for (int r = 0; r < 4; ++r) {
      int row = b * TT + q0 + wave * 16 + qd * 4 + r;
      int col = h * DH + ni * 16 + ln;
      O[(size_t)row * DM + col] = f2bf(o_acc[ni][r] / l_st[r]);
    }
}

extern "C" void kernel_launch(void* const* d_in, const int* in_sizes, int n_in,
                              void* d_out, int out_size, void* d_ws, size_t ws_size,
                              hipStream_t stream) {
  const float* x  = (const float*)d_in[0];
  const float* Wq = (const float*)d_in[1];
  const float* bq = (const float*)d_in[2];
  const float* Wk = (const float*)d_in[3];
  const float* bk = (const float*)d_in[4];
  const float* Wv = (const float*)d_in[5];
  const float* bv = (const float*)d_in[6];
  const float* Wo = (const float*)d_in[7];
  const float* bo = (const float*)d_in[8];

  char* ws = (char*)d_ws;
  const size_t MB = 1ull << 20;
  u16* xbf = (u16*)(ws + 0);        // 8 MB  (4096 x 1024 bf16)
  u16* Wqt = (u16*)(ws + 8 * MB);   // 2 MB each
  u16* Wkt = (u16*)(ws + 10 * MB);
  u16* Wvt = (u16*)(ws + 12 * MB);
  u16* Wot = (u16*)(ws + 14 * MB);
  u16* Qb  = (u16*)(ws + 16 * MB);  // 8 MB
  u16* Kb  = (u16*)(ws + 24 * MB);  // 8 MB
  u16* Vb  = (u16*)(ws + 32 * MB);  // 8 MB
  u16* Vtb = (u16*)(ws + 40 * MB);  // 8 MB
  u16* Ob  = (u16*)(ws + 48 * MB);  // 8 MB

  cvt_x_kernel<<<4096, 256, 0, stream>>>(x, xbf);
  transpose_w_kernel<<<dim3(16, 16, 4), 256, 0, stream>>>(Wq, Wk, Wv, Wo,
                                                          Wqt, Wkt, Wvt, Wot);
  gemm_bt_kernel<false><<<dim3(8, 32), 256, 0, stream>>>(xbf, Wqt, bq, Qb);
  gemm_bt_kernel<false><<<dim3(8, 32), 256, 0, stream>>>(xbf, Wkt, bk, Kb);
  gemm_bt_kernel<false><<<dim3(8, 32), 256, 0, stream>>>(xbf, Wvt, bv, Vb);
  transpose_v_kernel<<<dim3(32, 32), 256, 0, stream>>>(Vb, Vtb);
  flash_kernel<<<dim3(32, 32), 256, 0, stream>>>(Qb, Kb, Vtb, Ob);
  gemm_bt_kernel<true><<<dim3(8, 32), 256, 0, stream>>>(Ob, Wot, bo, (float*)d_out);
}

// Round 2
// 244.447 us; speedup vs baseline: 1.6032x; 1.6032x over previous
//
#include <hip/hip_runtime.h>

typedef unsigned short u16;
typedef unsigned int u32;

#define DM 1024
#define NH 16
#define DH 64
#define BB 2
#define TT 2048

using frag8  = __attribute__((ext_vector_type(8))) short;
using bf16x8 = __attribute__((ext_vector_type(8))) __bf16;
using f32x4  = __attribute__((ext_vector_type(4))) float;

__device__ inline u16 f2bf(float f) {
  union { float f; u32 u; } v; v.f = f;
  u32 r = v.u + 0x7fffu + ((v.u >> 16) & 1u);
  return (u16)(r >> 16);
}

__device__ inline f32x4 mfma_bf16(frag8 a, frag8 b, f32x4 c) {
  return __builtin_amdgcn_mfma_f32_16x16x32_bf16(
      __builtin_bit_cast(bf16x8, a), __builtin_bit_cast(bf16x8, b), c, 0, 0, 0);
}

// async global->LDS, 16B per lane; lds base must be wave-uniform
__device__ inline void gld16(void* lds, const void* g) {
  __builtin_amdgcn_global_load_lds(
      (const __attribute__((address_space(1))) void*)g,
      (__attribute__((address_space(3))) void*)lds, 16, 0, 0);
}

// ---------- x -> bf16 ----------
__global__ __launch_bounds__(256) void cvt_x_kernel(const float* __restrict__ X,
                                                    u16* __restrict__ Y) {
  int i = blockIdx.x * 256 + threadIdx.x;
  float4 v = ((const float4*)X)[i];
  ushort4 o;
  o.x = f2bf(v.x); o.y = f2bf(v.y); o.z = f2bf(v.z); o.w = f2bf(v.w);
  ((ushort4*)Y)[i] = o;
}

// ---------- W (K,N) fp32 -> Wt (N,K) bf16, tiled ----------
__global__ __launch_bounds__(256) void transpose_w_kernel(
    const float* __restrict__ W0, const float* __restrict__ W1,
    const float* __restrict__ W2, const float* __restrict__ W3,
    u16* __restrict__ O0, u16* __restrict__ O1,
    u16* __restrict__ O2, u16* __restrict__ O3) {
  const float* W; u16* Ot;
  switch (blockIdx.z) {
    case 0: W = W0; Ot = O0; break;
    case 1: W = W1; Ot = O1; break;
    case 2: W = W2; Ot = O2; break;
    default: W = W3; Ot = O3; break;
  }
  __shared__ u16 Ls[64][72];
  int tid = threadIdx.x;
  int n0 = blockIdx.x * 64;
  int k0 = blockIdx.y * 64;
#pragma unroll
  for (int p = 0; p < 4; ++p) {
    int id = tid + p * 256;
    int row = id >> 4;
    int c4 = (id & 15) * 4;
    float4 v = *(const float4*)&W[(size_t)(k0 + row) * DM + n0 + c4];
    ushort4 o; o.x = f2bf(v.x); o.y = f2bf(v.y); o.z = f2bf(v.z); o.w = f2bf(v.w);
    *(ushort4*)&Ls[row][c4] = o;
  }
  __syncthreads();
#pragma unroll
  for (int p = 0; p < 4; ++p) {
    int id = tid + p * 256;
    int row = id >> 4;
    int c4 = (id & 15) * 4;
    ushort4 o;
    o.x = Ls[c4 + 0][row]; o.y = Ls[c4 + 1][row];
    o.z = Ls[c4 + 2][row]; o.w = Ls[c4 + 3][row];
    *(ushort4*)&Ot[(size_t)(n0 + row) * DM + k0 + c4] = o;
  }
}

// ---------- m97-style GEMM: C = A @ Bt^T + bias ----------
// A: M x 1024 bf16 (stride 1024). Bt: N x 1024 bf16. 128x128 tile, BK=32.
// MODE 0: QKV output — n<2048 -> QK buf (stride 2048, bf16+bias),
//                      n>=2048 -> Vt transposed scatter (B,H,DH,TT) bf16+bias.
// MODE 1: f32 out (stride 1024) + bias b0.
template <int MODE>
__global__ __launch_bounds__(256) void gemm97_kernel(
    const u16* __restrict__ A, const u16* __restrict__ Bt,
    const float* __restrict__ b0, const float* __restrict__ b1,
    const float* __restrict__ b2,
    u16* __restrict__ QK, u16* __restrict__ Vt, float* __restrict__ Cf) {
  constexpr int K = 1024;
  __shared__ u16 As[128][32];
  __shared__ u16 Bs[128][32];
  int tid = threadIdx.x;
  int lane = tid & 63, w = tid >> 6;
  int qd = lane >> 4, ln = lane & 15;
  int wm = (w & 1) * 64, wn = (w >> 1) * 64;
  int m0 = blockIdx.y * 128, n0 = blockIdx.x * 128;
  f32x4 z = {0.f, 0.f, 0.f, 0.f};
  f32x4 acc[4][4];
#pragma unroll
  for (int mi = 0; mi < 4; ++mi)
#pragma unroll
    for (int ni = 0; ni < 4; ++ni) acc[mi][ni] = z;

  // staging addresses: wave w covers rows [w*32, w*32+32), lane l -> row w*32+(l>>2), chunk (l&3)*16B
  const u16* ga = A + (size_t)(m0 + w * 32 + (lane >> 2)) * K + (lane & 3) * 8;
  const u16* gb = Bt + (size_t)(n0 + w * 32 + (lane >> 2)) * K + (lane & 3) * 8;

  for (int k0 = 0; k0 < K; k0 += 32) {
    __syncthreads();
    gld16(&As[w * 32][0],      ga + k0);
    gld16(&As[w * 32 + 16][0], ga + k0 + 16 * K);
    gld16(&Bs[w * 32][0],      gb + k0);
    gld16(&Bs[w * 32 + 16][0], gb + k0 + 16 * K);
    __syncthreads();
    frag8 af[4], bf[4];
#pragma unroll
    for (int mi = 0; mi < 4; ++mi)
      af[mi] = *(const frag8*)&As[wm + mi * 16 + ln][qd * 8];
#pragma unroll
    for (int ni = 0; ni < 4; ++ni)
      bf[ni] = *(const frag8*)&Bs[wn + ni * 16 + ln][qd * 8];
#pragma unroll
    for (int mi = 0; mi < 4; ++mi)
#pragma unroll
      for (int ni = 0; ni < 4; ++ni)
        acc[mi][ni] = mfma_bf16(af[mi], bf[ni], acc[mi][ni]);
  }

#pragma unroll
  for (int ni = 0; ni < 4; ++ni) {
    int col = n0 + wn + ni * 16 + ln;
    if constexpr (MODE == 1) {
      float bias = b0[col];
#pragma unroll
      for (int mi = 0; mi < 4; ++mi) {
        int row = m0 + wm + mi * 16 + qd * 4;
#pragma unroll
        for (int r = 0; r < 4; ++r)
          Cf[(size_t)(row + r) * 1024 + col] = acc[mi][ni][r] + bias;
      }
    } else {
      if (col < 2048) {
        float bias = (col < 1024) ? b0[col] : b1[col - 1024];
#pragma unroll
        for (int mi = 0; mi < 4; ++mi) {
          int row = m0 + wm + mi * 16 + qd * 4;
#pragma unroll
          for (int r = 0; r < 4; ++r)
            QK[(size_t)(row + r) * 2048 + col] = f2bf(acc[mi][ni][r] + bias);
        }
      } else {
        int hv = col - 2048;
        int h = hv >> 6, d = hv & 63;
        float bias = b2[hv];
#pragma unroll
        for (int mi = 0; mi < 4; ++mi) {
          int row = m0 + wm + mi * 16 + qd * 4;
          int b = row >> 11, t = row & 2047;
          ushort4 pk;
          pk.x = f2bf(acc[mi][ni][0] + bias);
          pk.y = f2bf(acc[mi][ni][1] + bias);
          pk.z = f2bf(acc[mi][ni][2] + bias);
          pk.w = f2bf(acc[mi][ni][3] + bias);
          *(ushort4*)&Vt[(size_t)(((b << 4) + h) * 64 + d) * 2048 + t] = pk;
        }
      }
    }
  }
}

// ---------- flash attention v2: S^T formulation, 128-row Q block ----------
// QK buf: [B*T][2048] bf16 (Q cols 0..1023, K cols 1024..2047)
// Vt: [B*H][DH][TT] bf16. O: [B*T][1024] bf16.
#define SCL 0.18033688f  // 1/sqrt(64) * log2(e)
__global__ __launch_bounds__(256) void flash2_kernel(const u16* __restrict__ QK,
                                                     const u16* __restrict__ Vt,
                                                     u16* __restrict__ O) {
  // causal load balance: pair q-tile j with 15-j across grid halves
  int qt = (blockIdx.y < 16) ? (int)blockIdx.x : 15 - (int)blockIdx.x;
  int bh = blockIdx.y;
  int b = bh >> 4, h = bh & 15;
  int q0 = qt * 128;
  __shared__ u16 Ks[2][64][72];
  __shared__ u16 Vs[2][64][72];
  __shared__ u16 Ps[128][72];
  int tid = threadIdx.x;
  int lane = tid & 63, w = tid >> 6;
  int qd = lane >> 4, ln = lane & 15;

  // Q fragments (B-operand: n=ln -> q, k=qd*8+j -> d), direct from global
  frag8 qf[2][2];
#pragma unroll
  for (int nq = 0; nq < 2; ++nq)
#pragma unroll
    for (int kk = 0; kk < 2; ++kk)
      qf[nq][kk] = *(const frag8*)&QK[(size_t)(b * TT + q0 + w * 32 + nq * 16 + ln) * 2048 +
                                      h * 64 + kk * 32 + qd * 8];

  // staging: thread -> row tid>>2 (t for K, d for V), chunks (tid&3) and (tid&3)+4
  int srow = tid >> 2, seg = tid & 3;
  const u16* Kg = &QK[(size_t)(b * TT + srow) * 2048 + 1024 + h * 64 + seg * 8];
  const u16* Vg = &Vt[(size_t)(bh * 64 + srow) * 2048 + seg * 8];

  int nkt = 2 * qt + 2;

  // preload tile 0
  uint4 kr0 = *(const uint4*)&Kg[0];
  uint4 kr1 = *(const uint4*)&Kg[32];
  uint4 vr0 = *(const uint4*)&Vg[0];
  uint4 vr1 = *(const uint4*)&Vg[32];
  *(uint4*)&Ks[0][srow][seg * 8]      = kr0;
  *(uint4*)&Ks[0][srow][seg * 8 + 32] = kr1;
  *(uint4*)&Vs[0][srow][seg * 8]      = vr0;
  *(uint4*)&Vs[0][srow][seg * 8 + 32] = vr1;

  float m_st[2] = {-INFINITY, -INFINITY};
  float l_st[2] = {0.f, 0.f};
  f32x4 z = {0.f, 0.f, 0.f, 0.f};
  f32x4 o_acc[4][2];
#pragma unroll
  for (int mi = 0; mi < 4; ++mi) { o_acc[mi][0] = z; o_acc[mi][1] = z; }

  for (int kt = 0; kt < nkt; ++kt) {
    int cur = kt & 1;
    __syncthreads();  // buf[cur] staged & prior reads of buf[cur^1] done

    if (kt + 1 < nkt) {  // prefetch next tile to regs
      size_t ko = (size_t)(kt + 1) * 64 * 2048;
      int vo = (kt + 1) * 64;
      kr0 = *(const uint4*)&Kg[ko];
      kr1 = *(const uint4*)&Kg[ko + 32];
      vr0 = *(const uint4*)&Vg[vo];
      vr1 = *(const uint4*)&Vg[vo + 32];
    }

    // S^T = K Q^T : C col = q (ln), row = t (qd*4+reg)
    f32x4 s[4][2];
#pragma unroll
    for (int mi = 0; mi < 4; ++mi) { s[mi][0] = z; s[mi][1] = z; }
#pragma unroll
    for (int kk = 0; kk < 2; ++kk)
#pragma unroll
      for (int mi = 0; mi < 4; ++mi) {
        frag8 ak = *(const frag8*)&Ks[cur][mi * 16 + ln][kk * 32 + qd * 8];
        s[mi][0] = mfma_bf16(ak, qf[0][kk], s[mi][0]);
        s[mi][1] = mfma_bf16(ak, qf[1][kk], s[mi][1]);
      }

    // online softmax per 16-q band (state per lane: q = band+ln)
#pragma unroll
    for (int nq = 0; nq < 2; ++nq) {
      int qb = q0 + w * 32 + nq * 16;  // + ln per lane
      float sv[4][4];
      bool need_mask = (kt * 64 + 63) > qb;
#pragma unroll
      for (int mi = 0; mi < 4; ++mi)
#pragma unroll
        for (int r = 0; r < 4; ++r) {
          float v = s[mi][nq][r] * SCL;
          if (need_mask) {
            int t = kt * 64 + mi * 16 + qd * 4 + r;
            if (t > qb + ln) v = -INFINITY;
          }
          sv[mi][r] = v;
        }
      float mloc = sv[0][0];
#pragma unroll
      for (int mi = 0; mi < 4; ++mi)
#pragma unroll
        for (int r = 0; r < 4; ++r) mloc = fmaxf(mloc, sv[mi][r]);
      mloc = fmaxf(mloc, __shfl_xor(mloc, 16));
      mloc = fmaxf(mloc, __shfl_xor(mloc, 32));
      float mnew = fmaxf(m_st[nq], mloc);
      float alpha = exp2f(m_st[nq] - mnew);
      m_st[nq] = mnew;
      float ls = 0.f;
#pragma unroll
      for (int mi = 0; mi < 4; ++mi) {
        float p0 = exp2f(sv[mi][0] - mnew);
        float p1 = exp2f(sv[mi][1] - mnew);
        float p2 = exp2f(sv[mi][2] - mnew);
        float p3 = exp2f(sv[mi][3] - mnew);
        ls += (p0 + p1) + (p2 + p3);
        ushort4 pk;
        pk.x = f2bf(p0); pk.y = f2bf(p1); pk.z = f2bf(p2); pk.w = f2bf(p3);
        // P^T stored as [q][t]: 4 consecutive t per write (wave-private rows)
        *(ushort4*)&Ps[w * 32 + nq * 16 + ln][mi * 16 + qd * 4] = pk;
      }
      ls += __shfl_xor(ls, 16);
      ls += __shfl_xor(ls, 32);
      l_st[nq] = l_st[nq] * alpha + ls;
#pragma unroll
      for (int mi = 0; mi < 4; ++mi) o_acc[mi][nq] *= alpha;
    }

    // O^T += V^T P^T  (A = V^T tile (d x t), B = P^T from LDS, wave-local)
#pragma unroll
    for (int kk = 0; kk < 2; ++kk) {
      frag8 bp0 = *(const frag8*)&Ps[w * 32 + ln][kk * 32 + qd * 8];
      frag8 bp1 = *(const frag8*)&Ps[w * 32 + 16 + ln][kk * 32 + qd * 8];
#pragma unroll
      for (int mi = 0; mi < 4; ++mi) {
        frag8 av = *(const frag8*)&Vs[cur][mi * 16 + ln][kk * 32 + qd * 8];
        o_acc[mi][0] = mfma_bf16(av, bp0, o_acc[mi][0]);
        o_acc[mi][1] = mfma_bf16(av, bp1, o_acc[mi][1]);
      }
    }

    // write prefetched tile to buf[cur^1] (safe: its readers finished pre-barrier)
    if (kt + 1 < nkt) {
      int nxt = cur ^ 1;
      *(uint4*)&Ks[nxt][srow][seg * 8]      = kr0;
      *(uint4*)&Ks[nxt][srow][seg * 8 + 32] = kr1;
      *(uint4*)&Vs[nxt][srow][seg * 8]      = vr0;
      *(uint4*)&Vs[nxt][srow][seg * 8 + 32] = vr1;
    }
  }

  // epilogue: O[q][h*64+d] = o_acc / l  (4 consecutive d per store)
#pragma unroll
  for (int nq = 0; nq < 2; ++nq) {
    float rl = 1.0f / l_st[nq];
    size_t qrow = (size_t)(b * TT + q0 + w * 32 + nq * 16 + ln);
#pragma unroll
    for (int mi = 0; mi < 4; ++mi) {
      ushort4 ov;
      ov.x = f2bf(o_acc[mi][nq][0] * rl);
      ov.y = f2bf(o_acc[mi][nq][1] * rl);
      ov.z = f2bf(o_acc[mi][nq][2] * rl);
      ov.w = f2bf(o_acc[mi][nq][3] * rl);
      *(ushort4*)&O[qrow * DM + h * 64 + mi * 16 + qd * 4] = ov;
    }
  }
}

extern "C" void kernel_launch(void* const* d_in, const int* in_sizes, int n_in,
                              void* d_out, int out_size, void* d_ws, size_t ws_size,
                              hipStream_t stream) {
  const float* x  = (const float*)d_in[0];
  const float* Wq = (const float*)d_in[1];
  const float* bq = (const float*)d_in[2];
  const float* Wk = (const float*)d_in[3];
  const float* bk = (const float*)d_in[4];
  const float* Wv = (const float*)d_in[5];
  const float* bv = (const float*)d_in[6];
  const float* Wo = (const float*)d_in[7];
  const float* bo = (const float*)d_in[8];

  char* ws = (char*)d_ws;
  const size_t MB = 1ull << 20;
  u16* xbf  = (u16*)(ws + 0);         // 8 MB  (4096 x 1024)
  u16* Wcat = (u16*)(ws + 8 * MB);    // 6 MB  (3072 x 1024: Wq^T|Wk^T|Wv^T)
  u16* Wot  = (u16*)(ws + 14 * MB);   // 2 MB
  u16* QKb  = (u16*)(ws + 16 * MB);   // 16 MB (4096 x 2048)
  u16* Vtb  = (u16*)(ws + 32 * MB);   // 8 MB  (32 x 64 x 2048)
  u16* Ob   = (u16*)(ws + 40 * MB);   // 8 MB

  cvt_x_kernel<<<4096, 256, 0, stream>>>(x, xbf);
  transpose_w_kernel<<<dim3(16, 16, 4), 256, 0, stream>>>(
      Wq, Wk, Wv, Wo, Wcat, Wcat + 1024 * 1024, Wcat + 2 * 1024 * 1024, Wot);
  // fused QKV GEMM: N=3072
  gemm97_kernel<0><<<dim3(24, 32), 256, 0, stream>>>(
      xbf, Wcat, bq, bk, bv, QKb, Vtb, nullptr);
  flash2_kernel<<<dim3(16, 32), 256, 0, stream>>>(QKb, Vtb, Ob);
  gemm97_kernel<1><<<dim3(8, 32), 256, 0, stream>>>(
      Ob, Wot, bo, nullptr, nullptr, nullptr, nullptr, (float*)d_out);
}

// Round 3
// 222.370 us; speedup vs baseline: 1.7624x; 1.0993x over previous
//
#include <hip/hip_runtime.h>

typedef unsigned short u16;
typedef unsigned int u32;

#define DM 1024
#define NH 16
#define DH 64
#define BB 2
#define TT 2048

// Q pre-scale: (1/sqrt(64)) * log2(e)
#define SCLQ 0.18033688f

using frag8  = __attribute__((ext_vector_type(8))) short;
using bf16x8 = __attribute__((ext_vector_type(8))) __bf16;
using f32x4  = __attribute__((ext_vector_type(4))) float;

__device__ inline u16 f2bf(float f) {
  union { float f; u32 u; } v; v.f = f;
  u32 r = v.u + 0x7fffu + ((v.u >> 16) & 1u);
  return (u16)(r >> 16);
}

__device__ inline f32x4 mfma_bf16(frag8 a, frag8 b, f32x4 c) {
  return __builtin_amdgcn_mfma_f32_16x16x32_bf16(
      __builtin_bit_cast(bf16x8, a), __builtin_bit_cast(bf16x8, b), c, 0, 0, 0);
}

// async global->LDS, 16B/lane; LDS dest = base + lane*16 (wave-uniform base)
__device__ inline void gld16(void* lds, const void* g) {
  __builtin_amdgcn_global_load_lds(
      (const __attribute__((address_space(1))) void*)g,
      (__attribute__((address_space(3))) void*)lds, 16, 0, 0);
}

// swizzled LDS index (u16 units): row has 8 chunks of 8 u16 (16B);
// stored chunk position = chunk ^ (row & 7)  -> no padding, no 16B-granule conflicts
__device__ inline int swi(int row, int chunk) {
  return row * 64 + ((chunk ^ (row & 7)) << 3);
}

// ---------- x -> bf16 ----------
__global__ __launch_bounds__(256) void cvt_x_kernel(const float* __restrict__ X,
                                                    u16* __restrict__ Y) {
  int i = blockIdx.x * 256 + threadIdx.x;
  float4 v = ((const float4*)X)[i];
  ushort4 o;
  o.x = f2bf(v.x); o.y = f2bf(v.y); o.z = f2bf(v.z); o.w = f2bf(v.w);
  ((ushort4*)Y)[i] = o;
}

// ---------- W (K,N) fp32 -> Wt (N,K) bf16, tiled ----------
__global__ __launch_bounds__(256) void transpose_w_kernel(
    const float* __restrict__ W0, const float* __restrict__ W1,
    const float* __restrict__ W2, const float* __restrict__ W3,
    u16* __restrict__ O0, u16* __restrict__ O1,
    u16* __restrict__ O2, u16* __restrict__ O3) {
  const float* W; u16* Ot;
  switch (blockIdx.z) {
    case 0: W = W0; Ot = O0; break;
    case 1: W = W1; Ot = O1; break;
    case 2: W = W2; Ot = O2; break;
    default: W = W3; Ot = O3; break;
  }
  __shared__ u16 Ls[64][72];
  int tid = threadIdx.x;
  int n0 = blockIdx.x * 64;
  int k0 = blockIdx.y * 64;
#pragma unroll
  for (int p = 0; p < 4; ++p) {
    int id = tid + p * 256;
    int row = id >> 4;
    int c4 = (id & 15) * 4;
    float4 v = *(const float4*)&W[(size_t)(k0 + row) * DM + n0 + c4];
    ushort4 o; o.x = f2bf(v.x); o.y = f2bf(v.y); o.z = f2bf(v.z); o.w = f2bf(v.w);
    *(ushort4*)&Ls[row][c4] = o;
  }
  __syncthreads();
#pragma unroll
  for (int p = 0; p < 4; ++p) {
    int id = tid + p * 256;
    int row = id >> 4;
    int c4 = (id & 15) * 4;
    ushort4 o;
    o.x = Ls[c4 + 0][row]; o.y = Ls[c4 + 1][row];
    o.z = Ls[c4 + 2][row]; o.w = Ls[c4 + 3][row];
    *(ushort4*)&Ot[(size_t)(n0 + row) * DM + k0 + c4] = o;
  }
}

// ---------- m97-style GEMM: C = A @ Bt^T + bias ----------
// MODE 0: QKV (N=3072): col<1024 -> Q*(SCLQ) into QK; col<2048 -> K into QK;
//         col>=2048 -> V into Vb [4096][1024] (coalesced, transposed later).
// MODE 1: f32 out (stride 1024) + bias b0.
template <int MODE>
__global__ __launch_bounds__(256) void gemm97_kernel(
    const u16* __restrict__ A, const u16* __restrict__ Bt,
    const float* __restrict__ b0, const float* __restrict__ b1,
    const float* __restrict__ b2,
    u16* __restrict__ QK, u16* __restrict__ Vb, float* __restrict__ Cf) {
  constexpr int K = 1024;
  __shared__ u16 As[128][32];
  __shared__ u16 Bs[128][32];
  int tid = threadIdx.x;
  int lane = tid & 63, w = tid >> 6;
  int qd = lane >> 4, ln = lane & 15;
  int wm = (w & 1) * 64, wn = (w >> 1) * 64;
  int m0 = blockIdx.y * 128, n0 = blockIdx.x * 128;
  f32x4 z = {0.f, 0.f, 0.f, 0.f};
  f32x4 acc[4][4];
#pragma unroll
  for (int mi = 0; mi < 4; ++mi)
#pragma unroll
    for (int ni = 0; ni < 4; ++ni) acc[mi][ni] = z;

  const u16* ga = A + (size_t)(m0 + w * 32 + (lane >> 2)) * K + (lane & 3) * 8;
  const u16* gb = Bt + (size_t)(n0 + w * 32 + (lane >> 2)) * K + (lane & 3) * 8;

  for (int k0 = 0; k0 < K; k0 += 32) {
    __syncthreads();
    gld16(&As[w * 32][0],      ga + k0);
    gld16(&As[w * 32 + 16][0], ga + k0 + 16 * K);
    gld16(&Bs[w * 32][0],      gb + k0);
    gld16(&Bs[w * 32 + 16][0], gb + k0 + 16 * K);
    __syncthreads();
    frag8 af[4], bfr[4];
#pragma unroll
    for (int mi = 0; mi < 4; ++mi)
      af[mi] = *(const frag8*)&As[wm + mi * 16 + ln][qd * 8];
#pragma unroll
    for (int ni = 0; ni < 4; ++ni)
      bfr[ni] = *(const frag8*)&Bs[wn + ni * 16 + ln][qd * 8];
#pragma unroll
    for (int mi = 0; mi < 4; ++mi)
#pragma unroll
      for (int ni = 0; ni < 4; ++ni)
        acc[mi][ni] = mfma_bf16(af[mi], bfr[ni], acc[mi][ni]);
  }

#pragma unroll
  for (int ni = 0; ni < 4; ++ni) {
    int col = n0 + wn + ni * 16 + ln;
    if constexpr (MODE == 1) {
      float bias = b0[col];
#pragma unroll
      for (int mi = 0; mi < 4; ++mi) {
        int row = m0 + wm + mi * 16 + qd * 4;
#pragma unroll
        for (int r = 0; r < 4; ++r)
          Cf[(size_t)(row + r) * 1024 + col] = acc[mi][ni][r] + bias;
      }
    } else {
      if (col < 2048) {
        bool isq = col < 1024;
        float bias = isq ? b0[col] : b1[col - 1024];
#pragma unroll
        for (int mi = 0; mi < 4; ++mi) {
          int row = m0 + wm + mi * 16 + qd * 4;
#pragma unroll
          for (int r = 0; r < 4; ++r) {
            float v = acc[mi][ni][r] + bias;
            if (isq) v *= SCLQ;
            QK[(size_t)(row + r) * 2048 + col] = f2bf(v);
          }
        }
      } else {
        int c2 = col - 2048;
        float bias = b2[c2];
#pragma unroll
        for (int mi = 0; mi < 4; ++mi) {
          int row = m0 + wm + mi * 16 + qd * 4;
#pragma unroll
          for (int r = 0; r < 4; ++r)
            Vb[(size_t)(row + r) * 1024 + c2] = f2bf(acc[mi][ni][r] + bias);
        }
      }
    }
  }
}

// ---------- V (B,T,D) bf16 -> Vt (B,H,DH,T) bf16, tiled ----------
__global__ __launch_bounds__(256) void transpose_v_kernel(const u16* __restrict__ V,
                                                          u16* __restrict__ Vt) {
  int bh = blockIdx.y;
  int b = bh >> 4, h = bh & 15;
  int t0 = blockIdx.x * 64;
  __shared__ u16 Ls[64][72];
  int tid = threadIdx.x;
#pragma unroll
  for (int p = 0; p < 2; ++p) {
    int id = tid + p * 256;
    int row = id >> 3, seg = id & 7;
    *(uint4*)&Ls[row][seg * 8] =
        *(const uint4*)&V[(size_t)(b * TT + t0 + row) * DM + h * DH + seg * 8];
  }
  __syncthreads();
#pragma unroll
  for (int p = 0; p < 2; ++p) {
    int id = tid + p * 256;
    int d = id >> 3, seg = id & 7;
    union { u16 s[8]; uint4 v; } tmp;
#pragma unroll
    for (int j = 0; j < 8; ++j) tmp.s[j] = Ls[seg * 8 + j][d];
    *(uint4*)&Vt[(size_t)(bh * DH + d) * TT + t0 + seg * 8] = tmp.v;
  }
}

// ---------- flash v3: S^T form, fixed-max softmax, 64-q tiles, 40KB LDS ----------
// QK: [B*T][2048] bf16 (Q pre-scaled cols 0..1023, K cols 1024..2047)
// Vt: [B*H][DH][TT] bf16. O: [B*T][1024] bf16.
__global__ __launch_bounds__(256, 4) void flash3_kernel(const u16* __restrict__ QK,
                                                        const u16* __restrict__ Vt,
                                                        u16* __restrict__ O) {
  int qt = 31 - (int)blockIdx.x;  // longest blocks first
  int bh = blockIdx.y;
  int b = bh >> 4, h = bh & 15;
  int q0 = qt * 64;
  __shared__ u16 Ks[2 * 4096];
  __shared__ u16 Vs[2 * 4096];
  __shared__ u16 Ps[4096];
  int tid = threadIdx.x;
  int lane = tid & 63, w = tid >> 6;
  int qd = lane >> 4, ln = lane & 15;

  // Q fragments (B-operand: n=ln -> q, k=qd*8+j -> d); Q pre-scaled by SCLQ
  frag8 qf[2];
#pragma unroll
  for (int kk = 0; kk < 2; ++kk)
    qf[kk] = *(const frag8*)&QK[(size_t)(b * TT + q0 + w * 16 + ln) * 2048 +
                                h * 64 + kk * 32 + qd * 8];

  // per-lane global source for swizzled global_load_lds staging:
  // lane l -> LDS (wave base + l*16B) = row w*16 + (l>>3), chunk-pos l&7;
  // content chunk c = (l&7) ^ (l>>3)
  int lr = lane >> 3, lc = (lane & 7) ^ lr;
  const u16* KgA = &QK[(size_t)(b * TT + w * 16 + lr) * 2048 + 1024 + h * 64 + lc * 8];
  const u16* KgB = KgA + 8 * 2048;
  const u16* VgA = &Vt[(size_t)(bh * 64 + w * 16 + lr) * 2048 + lc * 8];
  const u16* VgB = VgA + 8 * 2048;
  int ldsw = w * 1024;  // u16 units: wave covers 2KB per buffer half

  int nkt = qt + 1;

  // preload tile 0 into buf 0
  gld16(&Ks[ldsw],       KgA);
  gld16(&Ks[ldsw + 512], KgB);
  gld16(&Vs[ldsw],       VgA);
  gld16(&Vs[ldsw + 512], VgB);

  float l_part = 0.f;
  f32x4 z = {0.f, 0.f, 0.f, 0.f};
  f32x4 o_acc[4] = {z, z, z, z};

  for (int kt = 0; kt < nkt; ++kt) {
    int cur = kt & 1;
    int cb = cur * 4096;
    __syncthreads();  // buf[cur] staged (vmcnt drained) & buf[cur^1] readers done

    if (kt + 1 < nkt) {  // async prefetch next tile into buf[cur^1]
      int nb = (cur ^ 1) * 4096;
      size_t ko = (size_t)(kt + 1) * 64 * 2048;
      int vo = (kt + 1) * 64;
      gld16(&Ks[nb + ldsw],       KgA + ko);
      gld16(&Ks[nb + ldsw + 512], KgB + ko);
      gld16(&Vs[nb + ldsw],       VgA + vo);
      gld16(&Vs[nb + ldsw + 512], VgB + vo);
    }

    bool diag = (kt == qt);

    // S^T = K Q^T : C col=ln -> q (w*16+ln), row=qd*4+r -> t (mi*16+qd*4+r)
    f32x4 s[4] = {z, z, z, z};
#pragma unroll
    for (int mi = 0; mi < 4; ++mi) {
      if (diag && mi > w) continue;  // fully masked band (wave-uniform)
#pragma unroll
      for (int kk = 0; kk < 2; ++kk) {
        frag8 ak = *(const frag8*)&Ks[cb + swi(mi * 16 + ln, 4 * kk + qd)];
        s[mi] = mfma_bf16(ak, qf[kk], s[mi]);
      }
    }

    // fixed-max softmax: p = exp2(s); l deferred to per-lane partial
#pragma unroll
    for (int mi = 0; mi < 4; ++mi) {
      int pb = swi(w * 16 + ln, 2 * mi + (qd >> 1)) + (qd & 1) * 4;
      if (diag && mi > w) {
        uint2 zz; zz.x = 0u; zz.y = 0u;
        *(uint2*)&Ps[pb] = zz;
        continue;
      }
      float p0 = __builtin_amdgcn_exp2f(s[mi][0]);
      float p1 = __builtin_amdgcn_exp2f(s[mi][1]);
      float p2 = __builtin_amdgcn_exp2f(s[mi][2]);
      float p3 = __builtin_amdgcn_exp2f(s[mi][3]);
      if (diag && mi == w) {  // partial mask: t_local = qd*4+r vs q_local = ln
        p0 = (qd * 4 + 0 <= ln) ? p0 : 0.f;
        p1 = (qd * 4 + 1 <= ln) ? p1 : 0.f;
        p2 = (qd * 4 + 2 <= ln) ? p2 : 0.f;
        p3 = (qd * 4 + 3 <= ln) ? p3 : 0.f;
      }
      l_part += (p0 + p1) + (p2 + p3);
      // round-half-up bf16 pack via v_perm
      u32 u0 = __builtin_bit_cast(u32, p0) + 0x8000u;
      u32 u1 = __builtin_bit_cast(u32, p1) + 0x8000u;
      u32 u2 = __builtin_bit_cast(u32, p2) + 0x8000u;
      u32 u3 = __builtin_bit_cast(u32, p3) + 0x8000u;
      uint2 pk;
      pk.x = __builtin_amdgcn_perm(u1, u0, 0x07060302u);
      pk.y = __builtin_amdgcn_perm(u3, u2, 0x07060302u);
      *(uint2*)&Ps[pb] = pk;  // wave-private rows; in-wave lgkm ordering suffices
    }

    // O^T += V^T P^T  (A = V^T (m=d,k=t), B = P^T (n=q,k=t))
#pragma unroll
    for (int kk = 0; kk < 2; ++kk) {
      if (diag && kk == 1 && w < 2) continue;  // t>=32 fully masked for w<2
      frag8 bp = *(const frag8*)&Ps[swi(w * 16 + ln, 4 * kk + qd)];
#pragma unroll
      for (int mi = 0; mi < 4; ++mi) {
        frag8 av = *(const frag8*)&Vs[cb + swi(mi * 16 + ln, 4 * kk + qd)];
        o_acc[mi] = mfma_bf16(av, bp, o_acc[mi]);
      }
    }
  }

  // final l reduction across quad groups (same q = ln in all quads)
  l_part += __shfl_xor(l_part, 16);
  l_part += __shfl_xor(l_part, 32);
  float rl = 1.0f / l_part;

#pragma unroll
  for (int mi = 0; mi < 4; ++mi) {
    ushort4 ov;
    ov.x = f2bf(o_acc[mi][0] * rl);
    ov.y = f2bf(o_acc[mi][1] * rl);
    ov.z = f2bf(o_acc[mi][2] * rl);
    ov.w = f2bf(o_acc[mi][3] * rl);
    *(ushort4*)&O[(size_t)(b * TT + q0 + w * 16 + ln) * DM + h * 64 + mi * 16 + qd * 4] = ov;
  }
}

extern "C" void kernel_launch(void* const* d_in, const int* in_sizes, int n_in,
                              void* d_out, int out_size, void* d_ws, size_t ws_size,
                              hipStream_t stream) {
  const float* x  = (const float*)d_in[0];
  const float* Wq = (const float*)d_in[1];
  const float* bq = (const float*)d_in[2];
  const float* Wk = (const float*)d_in[3];
  const float* bk = (const float*)d_in[4];
  const float* Wv = (const float*)d_in[5];
  const float* bv = (const float*)d_in[6];
  const float* Wo = (const float*)d_in[7];
  const float* bo = (const float*)d_in[8];

  char* ws = (char*)d_ws;
  const size_t MB = 1ull << 20;
  u16* xbf  = (u16*)(ws + 0);         // 8 MB  (4096 x 1024)
  u16* Wcat = (u16*)(ws + 8 * MB);    // 6 MB  (3072 x 1024: Wq^T|Wk^T|Wv^T)
  u16* Wot  = (u16*)(ws + 14 * MB);   // 2 MB
  u16* QKb  = (u16*)(ws + 16 * MB);   // 16 MB (4096 x 2048)
  u16* Vbb  = (u16*)(ws + 32 * MB);   // 8 MB  (4096 x 1024)
  u16* Vtb  = (u16*)(ws + 40 * MB);   // 8 MB  (32 x 64 x 2048)
  u16* Ob   = (u16*)(ws + 48 * MB);   // 8 MB

  cvt_x_kernel<<<4096, 256, 0, stream>>>(x, xbf);
  transpose_w_kernel<<<dim3(16, 16, 4), 256, 0, stream>>>(
      Wq, Wk, Wv, Wo, Wcat, Wcat + 1024 * 1024, Wcat + 2 * 1024 * 1024, Wot);
  gemm97_kernel<0><<<dim3(24, 32), 256, 0, stream>>>(
      xbf, Wcat, bq, bk, bv, QKb, Vbb, nullptr);
  transpose_v_kernel<<<dim3(32, 32), 256, 0, stream>>>(Vbb, Vtb);
  flash3_kernel<<<dim3(32, 32), 256, 0, stream>>>(QKb, Vtb, Ob);
  gemm97_kernel<1><<<dim3(8, 32), 256, 0, stream>>>(
      Ob, Wot, bo, nullptr, nullptr, nullptr, nullptr, (float*)d_out);
}

// Round 4
// 212.312 us; speedup vs baseline: 1.8459x; 1.0474x over previous
//
#include <hip/hip_runtime.h>

typedef unsigned short u16;
typedef unsigned int u32;

#define DM 1024
#define NH 16
#define DH 64
#define BB 2
#define TT 2048

// Q pre-scale: (1/sqrt(64)) * log2(e)
#define SCLQ 0.18033688f

using frag8  = __attribute__((ext_vector_type(8))) short;
using bf16x8 = __attribute__((ext_vector_type(8))) __bf16;
using f32x4  = __attribute__((ext_vector_type(4))) float;

__device__ inline u16 f2bf(float f) {
  union { float f; u32 u; } v; v.f = f;
  u32 r = v.u + 0x7fffu + ((v.u >> 16) & 1u);
  return (u16)(r >> 16);
}

__device__ inline f32x4 mfma_bf16(frag8 a, frag8 b, f32x4 c) {
  return __builtin_amdgcn_mfma_f32_16x16x32_bf16(
      __builtin_bit_cast(bf16x8, a), __builtin_bit_cast(bf16x8, b), c, 0, 0, 0);
}

// async global->LDS, 16B/lane; LDS dest = base + lane*16 (wave-uniform base)
__device__ inline void gld16(void* lds, const void* g) {
  __builtin_amdgcn_global_load_lds(
      (const __attribute__((address_space(1))) void*)g,
      (__attribute__((address_space(3))) void*)lds, 16, 0, 0);
}

// swizzled LDS index (u16 units): row = 8 chunks of 8 u16 (16B);
// stored chunk position = chunk ^ (row & 7)
__device__ inline int swi(int row, int chunk) {
  return row * 64 + ((chunk ^ (row & 7)) << 3);
}

// ---------- x -> bf16 ----------
__global__ __launch_bounds__(256) void cvt_x_kernel(const float* __restrict__ X,
                                                    u16* __restrict__ Y) {
  int i = blockIdx.x * 256 + threadIdx.x;
  float4 v = ((const float4*)X)[i];
  ushort4 o;
  o.x = f2bf(v.x); o.y = f2bf(v.y); o.z = f2bf(v.z); o.w = f2bf(v.w);
  ((ushort4*)Y)[i] = o;
}

// ---------- W (K,N) fp32 -> Wt (N,K) bf16, tiled ----------
__global__ __launch_bounds__(256) void transpose_w_kernel(
    const float* __restrict__ W0, const float* __restrict__ W1,
    const float* __restrict__ W2, const float* __restrict__ W3,
    u16* __restrict__ O0, u16* __restrict__ O1,
    u16* __restrict__ O2, u16* __restrict__ O3) {
  const float* W; u16* Ot;
  switch (blockIdx.z) {
    case 0: W = W0; Ot = O0; break;
    case 1: W = W1; Ot = O1; break;
    case 2: W = W2; Ot = O2; break;
    default: W = W3; Ot = O3; break;
  }
  __shared__ u16 Ls[64][72];
  int tid = threadIdx.x;
  int n0 = blockIdx.x * 64;
  int k0 = blockIdx.y * 64;
#pragma unroll
  for (int p = 0; p < 4; ++p) {
    int id = tid + p * 256;
    int row = id >> 4;
    int c4 = (id & 15) * 4;
    float4 v = *(const float4*)&W[(size_t)(k0 + row) * DM + n0 + c4];
    ushort4 o; o.x = f2bf(v.x); o.y = f2bf(v.y); o.z = f2bf(v.z); o.w = f2bf(v.w);
    *(ushort4*)&Ls[row][c4] = o;
  }
  __syncthreads();
#pragma unroll
  for (int p = 0; p < 4; ++p) {
    int id = tid + p * 256;
    int row = id >> 4;
    int c4 = (id & 15) * 4;
    ushort4 o;
    o.x = Ls[c4 + 0][row]; o.y = Ls[c4 + 1][row];
    o.z = Ls[c4 + 2][row]; o.w = Ls[c4 + 3][row];
    *(ushort4*)&Ot[(size_t)(n0 + row) * DM + k0 + c4] = o;
  }
}

// ---------- QKV GEMM (double-buffered, 1 barrier/iter): 128x128 tile ----------
// col<1024 -> Q*SCLQ into QK; col<2048 -> K into QK; col>=2048 -> V into Vb.
__global__ __launch_bounds__(256, 3) void gemm_qkv_kernel(
    const u16* __restrict__ A, const u16* __restrict__ Bt,
    const float* __restrict__ b0, const float* __restrict__ b1,
    const float* __restrict__ b2,
    u16* __restrict__ QK, u16* __restrict__ Vb) {
  constexpr int K = 1024;
  __shared__ u16 As[2][4096];  // [buf][128 rows x 32 k]
  __shared__ u16 Bs[2][4096];
  int tid = threadIdx.x;
  int lane = tid & 63, w = tid >> 6;
  int qd = lane >> 4, ln = lane & 15;
  int wm = (w & 1) * 64, wn = (w >> 1) * 64;
  int m0 = blockIdx.y * 128, n0 = blockIdx.x * 128;
  f32x4 z = {0.f, 0.f, 0.f, 0.f};
  f32x4 acc[4][4];
#pragma unroll
  for (int mi = 0; mi < 4; ++mi)
#pragma unroll
    for (int ni = 0; ni < 4; ++ni) acc[mi][ni] = z;

  const u16* ga = A + (size_t)(m0 + w * 32 + (lane >> 2)) * K + (lane & 3) * 8;
  const u16* gb = Bt + (size_t)(n0 + w * 32 + (lane >> 2)) * K + (lane & 3) * 8;

  // preload k0=0 into buf0
  gld16(&As[0][w * 1024],       ga);
  gld16(&As[0][w * 1024 + 512], ga + 16 * K);
  gld16(&Bs[0][w * 1024],       gb);
  gld16(&Bs[0][w * 1024 + 512], gb + 16 * K);

  for (int k0 = 0; k0 < K; k0 += 32) {
    int cur = (k0 >> 5) & 1;
    __syncthreads();  // drains prefetch for buf[cur]; prior reads of buf[cur^1] done
    if (k0 + 32 < K) {
      int nb = cur ^ 1;
      gld16(&As[nb][w * 1024],       ga + k0 + 32);
      gld16(&As[nb][w * 1024 + 512], ga + k0 + 32 + 16 * K);
      gld16(&Bs[nb][w * 1024],       gb + k0 + 32);
      gld16(&Bs[nb][w * 1024 + 512], gb + k0 + 32 + 16 * K);
    }
    frag8 af[4], bfr[4];
#pragma unroll
    for (int mi = 0; mi < 4; ++mi)
      af[mi] = *(const frag8*)&As[cur][(wm + mi * 16 + ln) * 32 + qd * 8];
#pragma unroll
    for (int ni = 0; ni < 4; ++ni)
      bfr[ni] = *(const frag8*)&Bs[cur][(wn + ni * 16 + ln) * 32 + qd * 8];
#pragma unroll
    for (int mi = 0; mi < 4; ++mi)
#pragma unroll
      for (int ni = 0; ni < 4; ++ni)
        acc[mi][ni] = mfma_bf16(af[mi], bfr[ni], acc[mi][ni]);
  }

#pragma unroll
  for (int ni = 0; ni < 4; ++ni) {
    int col = n0 + wn + ni * 16 + ln;
    if (col < 2048) {
      bool isq = col < 1024;
      float bias = isq ? b0[col] : b1[col - 1024];
#pragma unroll
      for (int mi = 0; mi < 4; ++mi) {
        int row = m0 + wm + mi * 16 + qd * 4;
#pragma unroll
        for (int r = 0; r < 4; ++r) {
          float v = acc[mi][ni][r] + bias;
          if (isq) v *= SCLQ;
          QK[(size_t)(row + r) * 2048 + col] = f2bf(v);
        }
      }
    } else {
      int c2 = col - 2048;
      float bias = b2[c2];
#pragma unroll
      for (int mi = 0; mi < 4; ++mi) {
        int row = m0 + wm + mi * 16 + qd * 4;
#pragma unroll
        for (int r = 0; r < 4; ++r)
          Vb[(size_t)(row + r) * 1024 + c2] = f2bf(acc[mi][ni][r] + bias);
      }
    }
  }
}

// ---------- out-proj GEMM (double-buffered): 128x64 tile, f32 out ----------
__global__ __launch_bounds__(256) void gemm_out_kernel(
    const u16* __restrict__ A, const u16* __restrict__ Bt,
    const float* __restrict__ b0, float* __restrict__ Cf) {
  constexpr int K = 1024;
  __shared__ u16 As[2][4096];  // 128 x 32
  __shared__ u16 Bs[2][2048];  // 64 x 32
  int tid = threadIdx.x;
  int lane = tid & 63, w = tid >> 6;
  int qd = lane >> 4, ln = lane & 15;
  int m0 = blockIdx.y * 128, n0 = blockIdx.x * 64;
  f32x4 z = {0.f, 0.f, 0.f, 0.f};
  f32x4 acc[2][4];
#pragma unroll
  for (int mi = 0; mi < 2; ++mi)
#pragma unroll
    for (int ni = 0; ni < 4; ++ni) acc[mi][ni] = z;

  const u16* ga = A + (size_t)(m0 + w * 32 + (lane >> 2)) * K + (lane & 3) * 8;
  const u16* gb = Bt + (size_t)(n0 + w * 16 + (lane >> 2)) * K + (lane & 3) * 8;

  gld16(&As[0][w * 1024],       ga);
  gld16(&As[0][w * 1024 + 512], ga + 16 * K);
  gld16(&Bs[0][w * 512],        gb);

  for (int k0 = 0; k0 < K; k0 += 32) {
    int cur = (k0 >> 5) & 1;
    __syncthreads();
    if (k0 + 32 < K) {
      int nb = cur ^ 1;
      gld16(&As[nb][w * 1024],       ga + k0 + 32);
      gld16(&As[nb][w * 1024 + 512], ga + k0 + 32 + 16 * K);
      gld16(&Bs[nb][w * 512],        gb + k0 + 32);
    }
    frag8 af[2], bfr[4];
#pragma unroll
    for (int mi = 0; mi < 2; ++mi)
      af[mi] = *(const frag8*)&As[cur][(w * 32 + mi * 16 + ln) * 32 + qd * 8];
#pragma unroll
    for (int ni = 0; ni < 4; ++ni)
      bfr[ni] = *(const frag8*)&Bs[cur][(ni * 16 + ln) * 32 + qd * 8];
#pragma unroll
    for (int mi = 0; mi < 2; ++mi)
#pragma unroll
      for (int ni = 0; ni < 4; ++ni)
        acc[mi][ni] = mfma_bf16(af[mi], bfr[ni], acc[mi][ni]);
  }

#pragma unroll
  for (int ni = 0; ni < 4; ++ni) {
    int col = n0 + ni * 16 + ln;
    float bias = b0[col];
#pragma unroll
    for (int mi = 0; mi < 2; ++mi) {
      int row = m0 + w * 32 + mi * 16 + qd * 4;
#pragma unroll
      for (int r = 0; r < 4; ++r)
        Cf[(size_t)(row + r) * 1024 + col] = acc[mi][ni][r] + bias;
    }
  }
}

// ---------- V (B,T,D) bf16 -> Vt (B,H,DH,T) bf16, tiled ----------
__global__ __launch_bounds__(256) void transpose_v_kernel(const u16* __restrict__ V,
                                                          u16* __restrict__ Vt) {
  int bh = blockIdx.y;
  int b = bh >> 4, h = bh & 15;
  int t0 = blockIdx.x * 64;
  __shared__ u16 Ls[64][72];
  int tid = threadIdx.x;
#pragma unroll
  for (int p = 0; p < 2; ++p) {
    int id = tid + p * 256;
    int row = id >> 3, seg = id & 7;
    *(uint4*)&Ls[row][seg * 8] =
        *(const uint4*)&V[(size_t)(b * TT + t0 + row) * DM + h * DH + seg * 8];
  }
  __syncthreads();
#pragma unroll
  for (int p = 0; p < 2; ++p) {
    int id = tid + p * 256;
    int d = id >> 3, seg = id & 7;
    union { u16 s[8]; uint4 v; } tmp;
#pragma unroll
    for (int j = 0; j < 8; ++j) tmp.s[j] = Ls[seg * 8 + j][d];
    *(uint4*)&Vt[(size_t)(bh * DH + d) * TT + t0 + seg * 8] = tmp.v;
  }
}

// ---------- flash v4: paired q-tiles (pj, 31-pj), uniform 33 MFMA-iters ----------
// QK: [B*T][2048] bf16 (Q pre-scaled, K). Vt: [B*H][DH][TT]. O: [B*T][1024] bf16.
__global__ __launch_bounds__(256, 3) void flash4_kernel(const u16* __restrict__ QK,
                                                        const u16* __restrict__ Vt,
                                                        u16* __restrict__ O) {
  int pj = blockIdx.x;            // 0..15
  int bh = blockIdx.y;
  int b = bh >> 4, h = bh & 15;
  int qtA = pj, qtB = 31 - pj;    // A's diag (kt=pj<=15) never equals B's (kt>=16)
  int q0A = qtA * 64, q0B = qtB * 64;
  __shared__ u16 Ks[2 * 4096];
  __shared__ u16 Vs[2 * 4096];
  __shared__ u16 PsA[4096];
  __shared__ u16 PsB[4096];
  int tid = threadIdx.x;
  int lane = tid & 63, w = tid >> 6;
  int qd = lane >> 4, ln = lane & 15;

  // Q fragments (B-operand: n=ln -> q, k=qd*8+j -> d); Q pre-scaled by SCLQ
  frag8 qfA[2], qfB[2];
#pragma unroll
  for (int kk = 0; kk < 2; ++kk) {
    qfA[kk] = *(const frag8*)&QK[(size_t)(b * TT + q0A + w * 16 + ln) * 2048 +
                                 h * 64 + kk * 32 + qd * 8];
    qfB[kk] = *(const frag8*)&QK[(size_t)(b * TT + q0B + w * 16 + ln) * 2048 +
                                 h * 64 + kk * 32 + qd * 8];
  }

  // swizzled global_load_lds staging (content chunk xor'ed into source addr)
  int lr = lane >> 3, lc = (lane & 7) ^ lr;
  const u16* KgA = &QK[(size_t)(b * TT + w * 16 + lr) * 2048 + 1024 + h * 64 + lc * 8];
  const u16* KgB = KgA + 8 * 2048;
  const u16* VgA = &Vt[(size_t)(bh * 64 + w * 16 + lr) * 2048 + lc * 8];
  const u16* VgB = VgA + 8 * 2048;
  int ldsw = w * 1024;

  int nkt = qtB + 1;

  gld16(&Ks[ldsw],       KgA);
  gld16(&Ks[ldsw + 512], KgB);
  gld16(&Vs[ldsw],       VgA);
  gld16(&Vs[ldsw + 512], VgB);

  float lA = 0.f, lB = 0.f;
  f32x4 z = {0.f, 0.f, 0.f, 0.f};
  f32x4 oA[4] = {z, z, z, z};
  f32x4 oB[4] = {z, z, z, z};

  for (int kt = 0; kt < nkt; ++kt) {
    int cur = kt & 1;
    int cb = cur * 4096;
    __syncthreads();

    if (kt + 1 < nkt) {
      int nb = (cur ^ 1) * 4096;
      size_t ko = (size_t)(kt + 1) * 64 * 2048;
      int vo = (kt + 1) * 64;
      gld16(&Ks[nb + ldsw],       KgA + ko);
      gld16(&Ks[nb + ldsw + 512], KgB + ko);
      gld16(&Vs[nb + ldsw],       VgA + vo);
      gld16(&Vs[nb + ldsw + 512], VgB + vo);
    }

    bool actA  = (kt <= qtA);
    bool diagA = (kt == qtA);
    bool diagB = (kt == qtB);

    // S^T = K Q^T for both tiles, sharing the K fragment loads
    f32x4 sA[4] = {z, z, z, z};
    f32x4 sB[4] = {z, z, z, z};
#pragma unroll
    for (int mi = 0; mi < 4; ++mi) {
      bool skipB = diagB && (mi > w);
      bool doA = actA && !(diagA && (mi > w));
      if (skipB && !doA) continue;
#pragma unroll
      for (int kk = 0; kk < 2; ++kk) {
        frag8 ak = *(const frag8*)&Ks[cb + swi(mi * 16 + ln, 4 * kk + qd)];
        if (!skipB) sB[mi] = mfma_bf16(ak, qfB[kk], sB[mi]);
        if (doA)    sA[mi] = mfma_bf16(ak, qfA[kk], sA[mi]);
      }
    }

    // fixed-max softmax + bf16 pack into P^T LDS
    auto softmax_store = [&](f32x4* s, bool diag, u16* Ps, float& lacc) {
#pragma unroll
      for (int mi = 0; mi < 4; ++mi) {
        int pb = swi(w * 16 + ln, 2 * mi + (qd >> 1)) + (qd & 1) * 4;
        if (diag && mi > w) {
          uint2 zz; zz.x = 0u; zz.y = 0u;
          *(uint2*)&Ps[pb] = zz;
          continue;
        }
        float p0 = __builtin_amdgcn_exp2f(s[mi][0]);
        float p1 = __builtin_amdgcn_exp2f(s[mi][1]);
        float p2 = __builtin_amdgcn_exp2f(s[mi][2]);
        float p3 = __builtin_amdgcn_exp2f(s[mi][3]);
        if (diag && mi == w) {
          p0 = (qd * 4 + 0 <= ln) ? p0 : 0.f;
          p1 = (qd * 4 + 1 <= ln) ? p1 : 0.f;
          p2 = (qd * 4 + 2 <= ln) ? p2 : 0.f;
          p3 = (qd * 4 + 3 <= ln) ? p3 : 0.f;
        }
        lacc += (p0 + p1) + (p2 + p3);
        u32 u0 = __builtin_bit_cast(u32, p0) + 0x8000u;
        u32 u1 = __builtin_bit_cast(u32, p1) + 0x8000u;
        u32 u2 = __builtin_bit_cast(u32, p2) + 0x8000u;
        u32 u3 = __builtin_bit_cast(u32, p3) + 0x8000u;
        uint2 pk;
        pk.x = __builtin_amdgcn_perm(u1, u0, 0x07060302u);
        pk.y = __builtin_amdgcn_perm(u3, u2, 0x07060302u);
        *(uint2*)&Ps[pb] = pk;
      }
    };
    softmax_store(sB, diagB, PsB, lB);
    if (actA) softmax_store(sA, diagA, PsA, lA);

    // O^T += V^T P^T, sharing the V fragment loads
#pragma unroll
    for (int kk = 0; kk < 2; ++kk) {
      if (diagB && kk == 1 && w < 2) continue;  // fully-masked half; A inactive here
      frag8 bpB = *(const frag8*)&PsB[swi(w * 16 + ln, 4 * kk + qd)];
      frag8 bpA;
      if (actA) bpA = *(const frag8*)&PsA[swi(w * 16 + ln, 4 * kk + qd)];
#pragma unroll
      for (int mi = 0; mi < 4; ++mi) {
        frag8 av = *(const frag8*)&Vs[cb + swi(mi * 16 + ln, 4 * kk + qd)];
        oB[mi] = mfma_bf16(av, bpB, oB[mi]);
        if (actA) oA[mi] = mfma_bf16(av, bpA, oA[mi]);
      }
    }
  }

  lA += __shfl_xor(lA, 16); lA += __shfl_xor(lA, 32);
  lB += __shfl_xor(lB, 16); lB += __shfl_xor(lB, 32);
  float rlA = 1.0f / lA, rlB = 1.0f / lB;

#pragma unroll
  for (int mi = 0; mi < 4; ++mi) {
    ushort4 ov;
    ov.x = f2bf(oA[mi][0] * rlA); ov.y = f2bf(oA[mi][1] * rlA);
    ov.z = f2bf(oA[mi][2] * rlA); ov.w = f2bf(oA[mi][3] * rlA);
    *(ushort4*)&O[(size_t)(b * TT + q0A + w * 16 + ln) * DM + h * 64 + mi * 16 + qd * 4] = ov;
    ov.x = f2bf(oB[mi][0] * rlB); ov.y = f2bf(oB[mi][1] * rlB);
    ov.z = f2bf(oB[mi][2] * rlB); ov.w = f2bf(oB[mi][3] * rlB);
    *(ushort4*)&O[(size_t)(b * TT + q0B + w * 16 + ln) * DM + h * 64 + mi * 16 + qd * 4] = ov;
  }
}

extern "C" void kernel_launch(void* const* d_in, const int* in_sizes, int n_in,
                              void* d_out, int out_size, void* d_ws, size_t ws_size,
                              hipStream_t stream) {
  const float* x  = (const float*)d_in[0];
  const float* Wq = (const float*)d_in[1];
  const float* bq = (const float*)d_in[2];
  const float* Wk = (const float*)d_in[3];
  const float* bk = (const float*)d_in[4];
  const float* Wv = (const float*)d_in[5];
  const float* bv = (const float*)d_in[6];
  const float* Wo = (const float*)d_in[7];
  const float* bo = (const float*)d_in[8];

  char* ws = (char*)d_ws;
  const size_t MB = 1ull << 20;
  u16* xbf  = (u16*)(ws + 0);         // 8 MB  (4096 x 1024)
  u16* Wcat = (u16*)(ws + 8 * MB);    // 6 MB  (3072 x 1024: Wq^T|Wk^T|Wv^T)
  u16* Wot  = (u16*)(ws + 14 * MB);   // 2 MB
  u16* QKb  = (u16*)(ws + 16 * MB);   // 16 MB (4096 x 2048)
  u16* Vbb  = (u16*)(ws + 32 * MB);   // 8 MB  (4096 x 1024)
  u16* Vtb  = (u16*)(ws + 40 * MB);   // 8 MB  (32 x 64 x 2048)
  u16* Ob   = (u16*)(ws + 48 * MB);   // 8 MB

  cvt_x_kernel<<<4096, 256, 0, stream>>>(x, xbf);
  transpose_w_kernel<<<dim3(16, 16, 4), 256, 0, stream>>>(
      Wq, Wk, Wv, Wo, Wcat, Wcat + 1024 * 1024, Wcat + 2 * 1024 * 1024, Wot);
  gemm_qkv_kernel<<<dim3(24, 32), 256, 0, stream>>>(
      xbf, Wcat, bq, bk, bv, QKb, Vbb);
  transpose_v_kernel<<<dim3(32, 32), 256, 0, stream>>>(Vbb, Vtb);
  flash4_kernel<<<dim3(16, 32), 256, 0, stream>>>(QKb, Vtb, Ob);
  gemm_out_kernel<<<dim3(16, 32), 256, 0, stream>>>(Ob, Wot, bo, (float*)d_out);
}